// Round 4
// baseline (137.061 us; speedup 1.0000x reference)
//
#include <hip/hip_runtime.h>
#include <stdint.h>

// SelfBallPointQuery: B=16, C=3, N=2048, RADIUS^2=0.04, MAX_SAMPLES=64.
// R21 = INSTRUMENTATION ROUND: byte-identical R20 kernel, launched 4x.
// The kernel is idempotent (reads pcs, fully overwrites out), so extra
// launches don't change the output. The per-iteration 256-MiB poison fill
// (~40.6us) outranks the kernel in rocprof's top-5 every round, so the
// kernel's own counters have never been visible; three structural rewrites
// of the test phase (R17 SMEM-heavy, R18 2x occupancy, R20 inverted
// broadcast + ballot) all moved dur by <=2us, leaving the location of the
// residual ~30us unproven. The slope K = (dur_R21 - dur_R20)/3 measures the
// true marginal kernel cost, discriminating "kernel ~26-30us (unmodeled
// stall)" vs "kernel ~10us + ~20us harness fixed cost" vs "harness floor".
// Kernel body unchanged from verified R20 (absmax 0.0).

#define B_DIM 16
#define N_PTS 2048
#define K_OUT 64
#define R2 0.04f
#define WAVES 16
#define BLOCK_T (WAVES * 64)            // 1024
#define JPW (N_PTS / WAVES)             // 128 points per wave
#define WPW (JPW / 32)                  // 4 mask words per lane
#define ROWPAD 65                       // LDS row stride

typedef float v2f __attribute__((ext_vector_type(2)));
typedef float f32x8 __attribute__((ext_vector_type(8)));

__global__ __launch_bounds__(BLOCK_T, 8) void ball_query_kernel(
    const float* __restrict__ pcs,   // (B, 3, N)
    int* __restrict__ out)           // (B, N, 64) int32
{
    __shared__ int rows[64 * ROWPAD];
    __shared__ int cntS[WAVES][64];
    __shared__ int qfS[WAVES][64];

    const int b    = blockIdx.x >> 5;
    const int qg   = blockIdx.x & 31;
    const int tid  = threadIdx.x;
    const int wave = __builtin_amdgcn_readfirstlane(tid >> 6); // uniform
    const int lane = tid & 63;

    const float* __restrict__ sx = pcs + (size_t)b * 3 * N_PTS;
    const float* __restrict__ sy = sx + N_PTS;
    const float* __restrict__ sz = sy + N_PTS;

    const int jbase = wave * JPW;
    const int qb    = qg * 64;
    int* const obase = out + (size_t)(b * N_PTS + qb) * K_OUT;

    // ---- wave-resident points: set0 = jbase+lane, set1 = jbase+64+lane ----
    v2f px, py, pz;
    px.x = sx[jbase + lane]; px.y = sx[jbase + 64 + lane];
    py.x = sy[jbase + lane]; py.y = sy[jbase + 64 + lane];
    pz.x = sz[jbase + lane]; pz.y = sz[jbase + 64 + lane];

    // per-lane mask words (lane = query), filled by guarded deposit
    unsigned w0 = 0, w1 = 0, w2 = 0, w3 = 0;

    #pragma unroll
    for (int c = 0; c < 8; ++c) {
        // 8 queries' coords per chunk, uniform address -> wide scalar loads
        const f32x8 qxv = *(const f32x8*)(sx + qb + c * 8);
        const f32x8 qyv = *(const f32x8*)(sy + qb + c * 8);
        const f32x8 qzv = *(const f32x8*)(sz + qb + c * 8);
        #pragma unroll
        for (int s = 0; s < 8; ++s) {
            const int q = c * 8 + s;
            // negate via sign-bit flip (exact)
            const unsigned bx = __float_as_uint(qxv[s]) ^ 0x80000000u;
            const unsigned by = __float_as_uint(qyv[s]) ^ 0x80000000u;
            const unsigned bz = __float_as_uint(qzv[s]) ^ 0x80000000u;
            v2f nX, nY, nZ;
            nX.x = nX.y = __uint_as_float(bx);
            nY.x = nY.y = __uint_as_float(by);
            nZ.x = nZ.y = __uint_as_float(bz);
            v2f dx, dy, dz, xx, yy, zz, s0, d2;
            asm("v_pk_add_f32 %0, %1, %2" : "=v"(dx) : "s"(nX), "v"(px));
            asm("v_pk_add_f32 %0, %1, %2" : "=v"(dy) : "s"(nY), "v"(py));
            asm("v_pk_add_f32 %0, %1, %2" : "=v"(dz) : "s"(nZ), "v"(pz));
            asm("v_pk_mul_f32 %0, %1, %1" : "=v"(xx) : "v"(dx));
            asm("v_pk_mul_f32 %0, %1, %1" : "=v"(yy) : "v"(dy));
            asm("v_pk_mul_f32 %0, %1, %1" : "=v"(zz) : "v"(dz));
            asm("v_pk_add_f32 %0, %1, %2" : "=v"(s0) : "v"(xx), "v"(yy));
            asm("v_pk_add_f32 %0, %1, %2" : "=v"(d2) : "v"(s0), "v"(zz));
            // wave-uniform hit masks: bit i == point jbase + (set*64) + i
            const unsigned long long b0 = __ballot(d2.x < R2);
            const unsigned long long b1 = __ballot(d2.y < R2);
            // deposit query q's 4 mask words into lane q (uniform sources)
            if (lane == q) {
                w0 = (unsigned)b0;
                w1 = (unsigned)(b0 >> 32);
                w2 = (unsigned)b1;
                w3 = (unsigned)(b1 >> 32);
            }
        }
    }

    unsigned mask[WPW] = { w0, w1, w2, w3 };

    // per-lane count + first hit within this wave's window
    int cnt = 0;
    #pragma unroll
    for (int t = 0; t < WPW; ++t) cnt += __builtin_popcount(mask[t]);
    int qf = -1;
    #pragma unroll
    for (int t = 0; t < WPW; ++t) {
        if (qf < 0 && mask[t] != 0u)
            qf = jbase + t * 32 + __builtin_ctz(mask[t]);
    }
    cntS[wave][lane] = cnt;
    qfS[wave][lane]  = qf;
    __syncthreads();

    // prefix over earlier waves' counts for my query; global first hit
    int base = 0, tc = 0, gfirst = 0;
    #pragma unroll
    for (int w = 0; w < WAVES; ++w) {
        const int c = cntS[w][lane];
        const int f = qfS[w][lane];
        if (w < wave) base += c;
        gfirst = (tc == 0 && c > 0) ? f : gfirst;
        tc += c;
    }

    // ---- sparse emit into LDS rows (disjoint slot ranges across waves) ----
    int slot = base;
    for (int t = 0; t < WPW; ++t) {
        unsigned m = mask[t];
        while (m != 0u && slot < K_OUT) {
            const int k = (int)__builtin_ctz(m);
            rows[lane * ROWPAD + slot] = jbase + t * 32 + k;
            m &= m - 1u;
            ++slot;
        }
    }

    // ---- pad: 4 slots per wave cover [0,64); fill gfirst where s >= tc ----
    #pragma unroll
    for (int s0i = 0; s0i < K_OUT / WAVES; ++s0i) {
        const int s = wave * (K_OUT / WAVES) + s0i;
        if (s >= tc) rows[lane * ROWPAD + s] = gfirst;
    }
    __syncthreads();

    // ---- coalesced copy-out: 64 rows x 64 ints ----
    #pragma unroll
    for (int it = 0; it < (64 * K_OUT) / BLOCK_T; ++it) {
        const int idx = it * BLOCK_T + tid;
        const int r = idx >> 6;
        const int c = idx & 63;
        obase[idx] = rows[r * ROWPAD + c];
    }
}

extern "C" void kernel_launch(void* const* d_in, const int* in_sizes, int n_in,
                              void* d_out, int out_size, void* d_ws, size_t ws_size,
                              hipStream_t stream) {
    const float* pcs = (const float*)d_in[0];
    int* out = (int*)d_out;
    const int grid = B_DIM * 32;     // 512 blocks
    // INSTRUMENTATION: 4 identical idempotent launches. Marginal slope
    // K = (dur_R21 - dur_R20)/3 = true per-launch kernel cost.
    for (int rep = 0; rep < 4; ++rep) {
        ball_query_kernel<<<grid, BLOCK_T, 0, stream>>>(pcs, out);
    }
}

// Round 5
// 121.593 us; speedup vs baseline: 1.1272x; 1.1272x over previous
//
#include <hip/hip_runtime.h>
#include <stdint.h>

// SelfBallPointQuery: B=16, C=3, N=2048, RADIUS^2=0.04, MAX_SAMPLES=64.
// R22 = PMC-VISIBILITY ROUND. R21's slope measured the true kernel cost at
// ~21us/launch (vs ~9us VALU-issue floor) with ~53us harness fixed cost.
// The ~41us poison fills have hidden the kernel from rocprof's top-5 in
// every round, so the stall responsible for the 2x gap has never been
// observable. Here the verified R20 body runs at grid x4 inside ONE
// dispatch (rep = blockIdx.x >> 9; all 4 reps write identical values to
// identical addresses -- benign, output unchanged). The ~84us dispatch
// outranks the fills, exposing VALUBusy / Occupancy / LDS_BANK_CONFLICT /
// FETCH_SIZE / VGPR_Count for the actual kernel.
// Decision tree: VALUBusy>=80% -> issue-bound, cut VALU/step (12 + bit
// transpose). VALUBusy<=55% low-conflict -> latency (SMEM chunk pipeline /
// branchless deposit). High LDS conflicts -> emit/copy-out. Low occupancy
// -> launch bounds.

#define B_DIM 16
#define N_PTS 2048
#define K_OUT 64
#define R2 0.04f
#define WAVES 16
#define BLOCK_T (WAVES * 64)            // 1024
#define JPW (N_PTS / WAVES)             // 128 points per wave
#define WPW (JPW / 32)                  // 4 mask words per lane
#define ROWPAD 65                       // LDS row stride
#define REPS 4                          // diagnostic work replication

typedef float v2f __attribute__((ext_vector_type(2)));
typedef float f32x8 __attribute__((ext_vector_type(8)));

__global__ __launch_bounds__(BLOCK_T, 8) void ball_query_kernel(
    const float* __restrict__ pcs,   // (B, 3, N)
    int* __restrict__ out)           // (B, N, 64) int32
{
    __shared__ int rows[64 * ROWPAD];
    __shared__ int cntS[WAVES][64];
    __shared__ int qfS[WAVES][64];

    const int bid  = blockIdx.x & 511;   // rep = blockIdx.x >> 9 (unused)
    const int b    = bid >> 5;
    const int qg   = bid & 31;
    const int tid  = threadIdx.x;
    const int wave = __builtin_amdgcn_readfirstlane(tid >> 6); // uniform
    const int lane = tid & 63;

    const float* __restrict__ sx = pcs + (size_t)b * 3 * N_PTS;
    const float* __restrict__ sy = sx + N_PTS;
    const float* __restrict__ sz = sy + N_PTS;

    const int jbase = wave * JPW;
    const int qb    = qg * 64;
    int* const obase = out + (size_t)(b * N_PTS + qb) * K_OUT;

    // ---- wave-resident points: set0 = jbase+lane, set1 = jbase+64+lane ----
    v2f px, py, pz;
    px.x = sx[jbase + lane]; px.y = sx[jbase + 64 + lane];
    py.x = sy[jbase + lane]; py.y = sy[jbase + 64 + lane];
    pz.x = sz[jbase + lane]; pz.y = sz[jbase + 64 + lane];

    // per-lane mask words (lane = query), filled by guarded deposit
    unsigned w0 = 0, w1 = 0, w2 = 0, w3 = 0;

    #pragma unroll
    for (int c = 0; c < 8; ++c) {
        // 8 queries' coords per chunk, uniform address -> wide scalar loads
        const f32x8 qxv = *(const f32x8*)(sx + qb + c * 8);
        const f32x8 qyv = *(const f32x8*)(sy + qb + c * 8);
        const f32x8 qzv = *(const f32x8*)(sz + qb + c * 8);
        #pragma unroll
        for (int s = 0; s < 8; ++s) {
            const int q = c * 8 + s;
            // negate via sign-bit flip (exact)
            const unsigned bx = __float_as_uint(qxv[s]) ^ 0x80000000u;
            const unsigned by = __float_as_uint(qyv[s]) ^ 0x80000000u;
            const unsigned bz = __float_as_uint(qzv[s]) ^ 0x80000000u;
            v2f nX, nY, nZ;
            nX.x = nX.y = __uint_as_float(bx);
            nY.x = nY.y = __uint_as_float(by);
            nZ.x = nZ.y = __uint_as_float(bz);
            v2f dx, dy, dz, xx, yy, zz, s0, d2;
            asm("v_pk_add_f32 %0, %1, %2" : "=v"(dx) : "s"(nX), "v"(px));
            asm("v_pk_add_f32 %0, %1, %2" : "=v"(dy) : "s"(nY), "v"(py));
            asm("v_pk_add_f32 %0, %1, %2" : "=v"(dz) : "s"(nZ), "v"(pz));
            asm("v_pk_mul_f32 %0, %1, %1" : "=v"(xx) : "v"(dx));
            asm("v_pk_mul_f32 %0, %1, %1" : "=v"(yy) : "v"(dy));
            asm("v_pk_mul_f32 %0, %1, %1" : "=v"(zz) : "v"(dz));
            asm("v_pk_add_f32 %0, %1, %2" : "=v"(s0) : "v"(xx), "v"(yy));
            asm("v_pk_add_f32 %0, %1, %2" : "=v"(d2) : "v"(s0), "v"(zz));
            // wave-uniform hit masks: bit i == point jbase + (set*64) + i
            const unsigned long long b0 = __ballot(d2.x < R2);
            const unsigned long long b1 = __ballot(d2.y < R2);
            // deposit query q's 4 mask words into lane q (uniform sources)
            if (lane == q) {
                w0 = (unsigned)b0;
                w1 = (unsigned)(b0 >> 32);
                w2 = (unsigned)b1;
                w3 = (unsigned)(b1 >> 32);
            }
        }
    }

    unsigned mask[WPW] = { w0, w1, w2, w3 };

    // per-lane count + first hit within this wave's window
    int cnt = 0;
    #pragma unroll
    for (int t = 0; t < WPW; ++t) cnt += __builtin_popcount(mask[t]);
    int qf = -1;
    #pragma unroll
    for (int t = 0; t < WPW; ++t) {
        if (qf < 0 && mask[t] != 0u)
            qf = jbase + t * 32 + __builtin_ctz(mask[t]);
    }
    cntS[wave][lane] = cnt;
    qfS[wave][lane]  = qf;
    __syncthreads();

    // prefix over earlier waves' counts for my query; global first hit
    int base = 0, tc = 0, gfirst = 0;
    #pragma unroll
    for (int w = 0; w < WAVES; ++w) {
        const int c = cntS[w][lane];
        const int f = qfS[w][lane];
        if (w < wave) base += c;
        gfirst = (tc == 0 && c > 0) ? f : gfirst;
        tc += c;
    }

    // ---- sparse emit into LDS rows (disjoint slot ranges across waves) ----
    int slot = base;
    for (int t = 0; t < WPW; ++t) {
        unsigned m = mask[t];
        while (m != 0u && slot < K_OUT) {
            const int k = (int)__builtin_ctz(m);
            rows[lane * ROWPAD + slot] = jbase + t * 32 + k;
            m &= m - 1u;
            ++slot;
        }
    }

    // ---- pad: 4 slots per wave cover [0,64); fill gfirst where s >= tc ----
    #pragma unroll
    for (int s0i = 0; s0i < K_OUT / WAVES; ++s0i) {
        const int s = wave * (K_OUT / WAVES) + s0i;
        if (s >= tc) rows[lane * ROWPAD + s] = gfirst;
    }
    __syncthreads();

    // ---- coalesced copy-out: 64 rows x 64 ints ----
    #pragma unroll
    for (int it = 0; it < (64 * K_OUT) / BLOCK_T; ++it) {
        const int idx = it * BLOCK_T + tid;
        const int r = idx >> 6;
        const int c = idx & 63;
        obase[idx] = rows[r * ROWPAD + c];
    }
}

extern "C" void kernel_launch(void* const* d_in, const int* in_sizes, int n_in,
                              void* d_out, int out_size, void* d_ws, size_t ws_size,
                              hipStream_t stream) {
    const float* pcs = (const float*)d_in[0];
    int* out = (int*)d_out;
    // ONE dispatch, 4x replicated grid: long enough (~84us) to outrank the
    // ~41us poison fills in rocprof's top-5 and expose the kernel's PMC.
    const int grid = B_DIM * 32 * REPS;  // 2048 blocks
    ball_query_kernel<<<grid, BLOCK_T, 0, stream>>>(pcs, out);
}

// Round 6
// 82.409 us; speedup vs baseline: 1.6632x; 1.4755x over previous
//
#include <hip/hip_runtime.h>
#include <stdint.h>

// SelfBallPointQuery: B=16, C=3, N=2048, RADIUS^2=0.04, MAX_SAMPLES=64.
// R23: VALU-minimal test phase. R22 PMC (4x-replicated dispatch) finally
// showed the kernel: VALUBusy 83-85%, HBM 1.6%, LDS conflicts ~1%, occ 77%
// -> pure VALU-issue-bound; K ~= 19-21us/launch vs ~53us harness fixed.
// R20's ballot+deposit path spent 7 VALU/step (2 cmp + cmp_eq + 4 cndmask)
// on mask plumbing alone. This round: R17's minimal bitpack (lane = query,
// m = m+m+cmp -> cmp+addc, no deposit/no transpose) fed from LDS broadcast
// instead of R17's serializing SMEM: each wave stages its 128-pt window to
// its own LDS strip once, then the unrolled inner loop reads point pairs
// at wave-uniform addresses with compile-time offsets (ds_read, DS pipe,
// conflict-free broadcast, zero VALU addressing). Per 4-point group:
// 16 pk + 4 cmp + 4 addc = 24 VALU for 256 tests; 32 groups/wave.
// FP exactness unchanged: d = (-q)+p (sign-flip exact), squares rounded
// individually, (x^2+y^2)+z^2 -- same sequence as verified R17/R20.
// Mask bit order: descending within each 4-group (k+3,k+2,k+1,k), groups
// descending -> point k lands at bit k (R17-verified scheme).
// Epilogue (count/qf/prefix/emit/pad/copy-out) byte-identical to R20.

#define B_DIM 16
#define N_PTS 2048
#define K_OUT 64
#define R2 0.04f
#define WAVES 16
#define BLOCK_T (WAVES * 64)            // 1024
#define JPW (N_PTS / WAVES)             // 128 points per wave
#define WPW (JPW / 32)                  // 4 mask words per lane
#define ROWPAD 65                       // LDS row stride

typedef float v2f __attribute__((ext_vector_type(2)));

__global__ __launch_bounds__(BLOCK_T, 8) void ball_query_kernel(
    const float* __restrict__ pcs,   // (B, 3, N)
    int* __restrict__ out)           // (B, N, 64) int32
{
    __shared__ v2f shp[WAVES][3][JPW / 2];   // per-wave point strips
    __shared__ int rows[64 * ROWPAD];
    __shared__ int cntS[WAVES][64];
    __shared__ int qfS[WAVES][64];

    const int b    = blockIdx.x >> 5;
    const int qg   = blockIdx.x & 31;
    const int tid  = threadIdx.x;
    const int wave = __builtin_amdgcn_readfirstlane(tid >> 6); // uniform
    const int lane = tid & 63;

    const float* __restrict__ sx = pcs + (size_t)b * 3 * N_PTS;
    const float* __restrict__ sy = sx + N_PTS;
    const float* __restrict__ sz = sy + N_PTS;

    const int jbase = wave * JPW;
    const int qb    = qg * 64;
    int* const obase = out + (size_t)(b * N_PTS + qb) * K_OUT;

    // ---- stage this wave's 128 points into its LDS strip (coalesced) ----
    shp[wave][0][lane] = *(const v2f*)(sx + jbase + 2 * lane);
    shp[wave][1][lane] = *(const v2f*)(sy + jbase + 2 * lane);
    shp[wave][2][lane] = *(const v2f*)(sz + jbase + 2 * lane);

    // ---- per-lane query, pre-negated, duplicated into both v2f halves ----
    const int qi = qb + lane;
    const float nx = -sx[qi], ny = -sy[qi], nz = -sz[qi];
    const v2f nqx = {nx, nx}, nqy = {ny, ny}, nqz = {nz, nz};

    __syncthreads();   // staging visible (also orders cross-lane LDS reads)

    // ---- dense test phase: 4 words x 32 bits, 4 points per group ----
    unsigned mask[WPW];
    #pragma unroll
    for (int t = 0; t < WPW; ++t) {
        unsigned m = 0;
        #pragma unroll
        for (int g = 28; g >= 0; g -= 4) {        // descending 4-groups
            const int p = (t * 32 + g) >> 1;      // v2f pair index (uniform)
            const v2f xlo = shp[wave][0][p], xhi = shp[wave][0][p + 1];
            const v2f ylo = shp[wave][1][p], yhi = shp[wave][1][p + 1];
            const v2f zlo = shp[wave][2][p], zhi = shp[wave][2][p + 1];
            v2f dxl, dyl, dzl, xxl, yyl, zzl, s0l, d2l;
            v2f dxh, dyh, dzh, xxh, yyh, zzh, s0h, d2h;
            asm("v_pk_add_f32 %0, %1, %2" : "=v"(dxl) : "v"(xlo), "v"(nqx));
            asm("v_pk_add_f32 %0, %1, %2" : "=v"(dyl) : "v"(ylo), "v"(nqy));
            asm("v_pk_add_f32 %0, %1, %2" : "=v"(dzl) : "v"(zlo), "v"(nqz));
            asm("v_pk_add_f32 %0, %1, %2" : "=v"(dxh) : "v"(xhi), "v"(nqx));
            asm("v_pk_add_f32 %0, %1, %2" : "=v"(dyh) : "v"(yhi), "v"(nqy));
            asm("v_pk_add_f32 %0, %1, %2" : "=v"(dzh) : "v"(zhi), "v"(nqz));
            asm("v_pk_mul_f32 %0, %1, %1" : "=v"(xxl) : "v"(dxl));
            asm("v_pk_mul_f32 %0, %1, %1" : "=v"(yyl) : "v"(dyl));
            asm("v_pk_mul_f32 %0, %1, %1" : "=v"(zzl) : "v"(dzl));
            asm("v_pk_mul_f32 %0, %1, %1" : "=v"(xxh) : "v"(dxh));
            asm("v_pk_mul_f32 %0, %1, %1" : "=v"(yyh) : "v"(dyh));
            asm("v_pk_mul_f32 %0, %1, %1" : "=v"(zzh) : "v"(dzh));
            asm("v_pk_add_f32 %0, %1, %2" : "=v"(s0l) : "v"(xxl), "v"(yyl));
            asm("v_pk_add_f32 %0, %1, %2" : "=v"(s0h) : "v"(xxh), "v"(yyh));
            asm("v_pk_add_f32 %0, %1, %2" : "=v"(d2l) : "v"(s0l), "v"(zzl));
            asm("v_pk_add_f32 %0, %1, %2" : "=v"(d2h) : "v"(s0h), "v"(zzh));
            // descending deposit: bits g+3, g+2, g+1, g  (point g+i -> bit g+i)
            m = m + m + (unsigned)(d2h.y < R2);
            m = m + m + (unsigned)(d2h.x < R2);
            m = m + m + (unsigned)(d2l.y < R2);
            m = m + m + (unsigned)(d2l.x < R2);
        }
        mask[t] = m;
    }

    // per-lane count + first hit within this wave's window
    int cnt = 0;
    #pragma unroll
    for (int t = 0; t < WPW; ++t) cnt += __builtin_popcount(mask[t]);
    int qf = -1;
    #pragma unroll
    for (int t = 0; t < WPW; ++t) {
        if (qf < 0 && mask[t] != 0u)
            qf = jbase + t * 32 + __builtin_ctz(mask[t]);
    }
    cntS[wave][lane] = cnt;
    qfS[wave][lane]  = qf;
    __syncthreads();

    // prefix over earlier waves' counts for my query; global first hit
    int base = 0, tc = 0, gfirst = 0;
    #pragma unroll
    for (int w = 0; w < WAVES; ++w) {
        const int c = cntS[w][lane];
        const int f = qfS[w][lane];
        if (w < wave) base += c;
        gfirst = (tc == 0 && c > 0) ? f : gfirst;
        tc += c;
    }

    // ---- sparse emit into LDS rows (disjoint slot ranges across waves) ----
    int slot = base;
    for (int t = 0; t < WPW; ++t) {
        unsigned m = mask[t];
        while (m != 0u && slot < K_OUT) {
            const int k = (int)__builtin_ctz(m);
            rows[lane * ROWPAD + slot] = jbase + t * 32 + k;
            m &= m - 1u;
            ++slot;
        }
    }

    // ---- pad: 4 slots per wave cover [0,64); fill gfirst where s >= tc ----
    #pragma unroll
    for (int s0i = 0; s0i < K_OUT / WAVES; ++s0i) {
        const int s = wave * (K_OUT / WAVES) + s0i;
        if (s >= tc) rows[lane * ROWPAD + s] = gfirst;
    }
    __syncthreads();

    // ---- coalesced copy-out: 64 rows x 64 ints ----
    #pragma unroll
    for (int it = 0; it < (64 * K_OUT) / BLOCK_T; ++it) {
        const int idx = it * BLOCK_T + tid;
        const int r = idx >> 6;
        const int c = idx & 63;
        obase[idx] = rows[r * ROWPAD + c];
    }
}

extern "C" void kernel_launch(void* const* d_in, const int* in_sizes, int n_in,
                              void* d_out, int out_size, void* d_ws, size_t ws_size,
                              hipStream_t stream) {
    const float* pcs = (const float*)d_in[0];
    int* out = (int*)d_out;
    const int grid = B_DIM * 32;     // 512 blocks
    ball_query_kernel<<<grid, BLOCK_T, 0, stream>>>(pcs, out);
}